// Round 7
// baseline (137.311 us; speedup 1.0000x reference)
//
#include <hip/hip_runtime.h>
#include <math.h>

// Chamfer distance, B=4, N=M=8192, fp32.
// Output layout (flat float32): dist1[B*N], dist2[B*M], idx1[B*N] (as float),
// idx2[B*M] (as float).
//
// R16: remove the DS pipe from the main loop. Evidence: R12 (d-form, 228
// VALU/group, 6 ds_read_b128) and R15 (e-form, 132 VALU/group, 8 ds_read)
// BOTH run 72us; real VALUBusy 68% vs 48%. Sum-model fits: DS-pipe occupancy
// (~12cy/broadcast b128, m134) + VALU with ~no overlap (phase-locked waves,
// per-group LDS->compute dependency; R10 prefetch null confirmed). So: stage
// NOTHING in LDS. A prep kernel writes an augmented float4 cloud (x,y,z,rr)
// to workspace; the main loop reads 8-point groups via WAVE-UNIFORM loads
// from it (const __restrict__, blockIdx/loop-derived address -> compiler
// emits scalar s_load on the SMEM/K$ pipe, or at worst uniform VMEM via L1
// broadcast). Zero DS instructions, no staging, no __syncthreads.
//
// e-form + guard unchanged from R15 (absmax 0 proven): e = fma(ax,rx,
// fma(ay,ry,fma(az,rz,rr))), a=-2q exact. If top-2 group-min e-gap <=
// eps=4e-6*(qq+2Rb) (2x margin over the ~1.9e-6*(qq+2Rb) bound,
// Rb=(|q|+sqrt(d1+.01))^2), replay the e-pass (same inputs -> bitwise same)
// to build a contender bitmask, then resolve exactly with R12's d-form
// ascending strict-< scan. Unflagged winner group provably == R12's; its
// exact d comes from a divergent global gather (L1/L2-resident). Same
// (d_bits<<32|global_group) atomic; chamfer_final unchanged -> outputs
// bitwise identical to R12/R15.
//
// ws layout: [pp 2*B*NQ*8][aug (B*N+B*M)*16]. If ws_size < that, fall back
// to the proven R15 LDS kernel (host-side branch; graph-safe).
//
// R13 lesson: named float4s + constant-index scalars only (no runtime-
// indexed arrays -> no scratch).

#define QPT 4         // queries per thread
#define BLK 256       // threads per block
#define QPB (QPT*BLK) // queries per block = 1024

// e-form group min over named float4s f0..f7
#define EMIN8(AX, AY, AZ, MOUT) do {                                          \
    float d0 = fmaf(AX, f0.x, fmaf(AY, f0.y, fmaf(AZ, f0.z, f0.w)));          \
    float d1 = fmaf(AX, f1.x, fmaf(AY, f1.y, fmaf(AZ, f1.z, f1.w)));          \
    float d2 = fmaf(AX, f2.x, fmaf(AY, f2.y, fmaf(AZ, f2.z, f2.w)));          \
    float d3 = fmaf(AX, f3.x, fmaf(AY, f3.y, fmaf(AZ, f3.z, f3.w)));          \
    float d4 = fmaf(AX, f4.x, fmaf(AY, f4.y, fmaf(AZ, f4.z, f4.w)));          \
    float d5 = fmaf(AX, f5.x, fmaf(AY, f5.y, fmaf(AZ, f5.z, f5.w)));          \
    float d6 = fmaf(AX, f6.x, fmaf(AY, f6.y, fmaf(AZ, f6.z, f6.w)));          \
    float d7 = fmaf(AX, f7.x, fmaf(AY, f7.y, fmaf(AZ, f7.z, f7.w)));          \
    float t0 = fminf(fminf(d0, d1), d2);                                      \
    float t1 = fminf(fminf(d3, d4), d5);                                      \
    float t2 = fminf(fminf(d6, d7), t0);                                      \
    MOUT = fminf(t1, t2);                                                     \
} while (0)

// exact d-form group min over named float4s f0..f7 (R12 expression; min is
// exact and tree-shape independent -> bitwise-compatible with chamfer_final)
#define DMIN8(QX, QY, QZ, MOUT) do {                                          \
    float dx, dy, dz;                                                         \
    dx = QX - f0.x; dy = QY - f0.y; dz = QZ - f0.z;                           \
    float d0 = fmaf(dx, dx, fmaf(dy, dy, dz * dz));                           \
    dx = QX - f1.x; dy = QY - f1.y; dz = QZ - f1.z;                           \
    float d1 = fmaf(dx, dx, fmaf(dy, dy, dz * dz));                           \
    dx = QX - f2.x; dy = QY - f2.y; dz = QZ - f2.z;                           \
    float d2 = fmaf(dx, dx, fmaf(dy, dy, dz * dz));                           \
    dx = QX - f3.x; dy = QY - f3.y; dz = QZ - f3.z;                           \
    float d3 = fmaf(dx, dx, fmaf(dy, dy, dz * dz));                           \
    dx = QX - f4.x; dy = QY - f4.y; dz = QZ - f4.z;                           \
    float d4 = fmaf(dx, dx, fmaf(dy, dy, dz * dz));                           \
    dx = QX - f5.x; dy = QY - f5.y; dz = QZ - f5.z;                           \
    float d5 = fmaf(dx, dx, fmaf(dy, dy, dz * dz));                           \
    dx = QX - f6.x; dy = QY - f6.y; dz = QZ - f6.z;                           \
    float d6 = fmaf(dx, dx, fmaf(dy, dy, dz * dz));                           \
    dx = QX - f7.x; dy = QY - f7.y; dz = QZ - f7.z;                           \
    float d7 = fmaf(dx, dx, fmaf(dy, dy, dz * dz));                           \
    float t0 = fminf(fminf(d0, d1), d2);                                      \
    float t1 = fminf(fminf(d3, d4), d5);                                      \
    float t2 = fminf(fminf(d6, d7), t0);                                      \
    MOUT = fminf(t1, t2);                                                     \
} while (0)

// build augmented cloud: aug[i] = (x,y,z,|p|^2) for [xyz1 | xyz2] concat
__global__ __launch_bounds__(256) void chamfer_prep(
    const float* __restrict__ xyz1, const float* __restrict__ xyz2,
    float4* __restrict__ aug, int n1, int total)
{
    const int i = blockIdx.x * blockDim.x + threadIdx.x;
    if (i >= total) return;
    const float* src = (i < n1) ? (xyz1 + 3 * (size_t)i)
                                : (xyz2 + 3 * (size_t)(i - n1));
    float gx = src[0], gy = src[1], gz = src[2];
    float rr = fmaf(gz, gz, fmaf(gy, gy, gx * gx));
    float4 f; f.x = gx; f.y = gy; f.z = gz; f.w = rr;
    aug[i] = f;
}

__global__ __launch_bounds__(256, 4) void chamfer_main_aug(
    const float* __restrict__ xyz1, const float* __restrict__ xyz2,
    const float4* __restrict__ aug,
    unsigned long long* __restrict__ pp,
    int N, int M, int B, int S, int C)
{
    const int dir = blockIdx.z;          // 0: xyz1->xyz2, 1: xyz2->xyz1
    const float* q = dir ? xyz2 : xyz1;  // query cloud (raw packed xyz)
    const int Nq = dir ? M : N;
    const int Nr = dir ? N : M;
    const int b     = blockIdx.y / S;
    const int split = blockIdx.y % S;
    const int base  = split * C;         // this block's ref-index range

    // ref group stream: wave-uniform address -> scalar/L1-broadcast loads.
    // dir 0 refs xyz2 (aug offset B*N), dir 1 refs xyz1 (aug offset 0).
    const float4* ag = aug + (dir ? 0 : (size_t)B * N) + (size_t)b * Nr + base;

    // load 4 query points; keep a = -2*q (exact; q recoverable as -0.5*a)
    float ax[QPT], ay[QPT], az[QPT];
    int qi[QPT];
    bool qvv[QPT];
#pragma unroll
    for (int k = 0; k < QPT; ++k) {
        qi[k] = blockIdx.x * QPB + k * BLK + threadIdx.x;
        qvv[k] = qi[k] < Nq;
        const float* qp = q + ((size_t)b * Nq + (qvv[k] ? qi[k] : 0)) * 3;
        ax[k] = -2.0f * qp[0]; ay[k] = -2.0f * qp[1]; az[k] = -2.0f * qp[2];
    }

    // per-query: top-2 group-min e values + winning group id
    float e1[QPT], e2[QPT];
    int   g1[QPT];
#pragma unroll
    for (int k = 0; k < QPT; ++k) { e1[k] = INFINITY; e2[k] = INFINITY; g1[k] = 0; }

    const int iters = C / 8;             // <= 64 (mask is u64)
    for (int j8 = 0; j8 < iters; ++j8) {
        const float4 f0 = ag[8 * j8 + 0];
        const float4 f1 = ag[8 * j8 + 1];
        const float4 f2 = ag[8 * j8 + 2];
        const float4 f3 = ag[8 * j8 + 3];
        const float4 f4 = ag[8 * j8 + 4];
        const float4 f5 = ag[8 * j8 + 5];
        const float4 f6 = ag[8 * j8 + 6];
        const float4 f7 = ag[8 * j8 + 7];
#pragma unroll
        for (int k = 0; k < QPT; ++k) {
            float m;
            EMIN8(ax[k], ay[k], az[k], m);
            float h = fmaxf(e1[k], m);
            e2[k] = fminf(e2[k], h);     // runner-up group-min
            if (m < e1[k]) g1[k] = j8;   // strict <: earliest group on e-ties
            e1[k] = fminf(e1[k], m);
        }
    }

    const size_t obase = (size_t)(dir * B + b) * Nq;
    const int gbase = split * (C / 8);   // global group base for this block
#pragma unroll
    for (int k = 0; k < QPT; ++k) {
        if (!qvv[k]) continue;
        // exact query coords (bitwise original: a = -2q exact, -0.5*a = q)
        const float qx = -0.5f * ax[k], qy = -0.5f * ay[k], qz = -0.5f * az[k];
        int gi = g1[k];
        float dwin;
        bool resolved = false;
        {
            // eps: contenders have rr <= Rb=(|q|+sqrt(d1e+0.01))^2; e-chain
            // error < ~1.9e-6*(qq+2Rb); use 4e-6 (2x margin).
            float qq  = fmaf(qx, qx, fmaf(qy, qy, qz * qz));
            float d1e = qq + e1[k];
            float rt  = sqrtf(qq) + sqrtf(fmaxf(d1e, 0.0f) + 0.01f);
            float eps = 4e-6f * fmaf(2.0f, rt * rt, qq);
            if (e2[k] - e1[k] <= eps) {
                // replay e-pass (same inputs -> bitwise same) -> contender mask
                const float lim = e1[k] + eps;
                unsigned long long mask = 0ull;
                for (int j8 = 0; j8 < iters; ++j8) {
                    const float4 f0 = ag[8 * j8 + 0];
                    const float4 f1 = ag[8 * j8 + 1];
                    const float4 f2 = ag[8 * j8 + 2];
                    const float4 f3 = ag[8 * j8 + 3];
                    const float4 f4 = ag[8 * j8 + 4];
                    const float4 f5 = ag[8 * j8 + 5];
                    const float4 f6 = ag[8 * j8 + 6];
                    const float4 f7 = ag[8 * j8 + 7];
                    float m;
                    EMIN8(ax[k], ay[k], az[k], m);
                    if (m <= lim) mask |= 1ull << j8;
                }
                // exact resolve with R12's d-form + semantics (earliest group)
                float bdx = INFINITY; int gs = 0;
                for (int j8 = 0; j8 < iters; ++j8) {
                    if (!((mask >> j8) & 1)) continue;
                    const float4 f0 = ag[8 * j8 + 0];
                    const float4 f1 = ag[8 * j8 + 1];
                    const float4 f2 = ag[8 * j8 + 2];
                    const float4 f3 = ag[8 * j8 + 3];
                    const float4 f4 = ag[8 * j8 + 4];
                    const float4 f5 = ag[8 * j8 + 5];
                    const float4 f6 = ag[8 * j8 + 6];
                    const float4 f7 = ag[8 * j8 + 7];
                    float md;
                    DMIN8(qx, qy, qz, md);
                    if (md < bdx) { bdx = md; gs = j8; }
                }
                gi = gs; dwin = bdx; resolved = true;
            }
        }
        if (!resolved) {
            // exact d-form min of winner group via divergent global gather
            // (L1/L2-resident; same xyz bits -> identical d bits).
            const float4* gv = ag + (size_t)gi * 8;
            const float4 f0 = gv[0], f1 = gv[1], f2 = gv[2], f3 = gv[3],
                         f4 = gv[4], f5 = gv[5], f6 = gv[6], f7 = gv[7];
            DMIN8(qx, qy, qz, dwin);
        }
        unsigned long long packed =
            ((unsigned long long)__float_as_uint(dwin) << 32)
            | (unsigned)(gbase + gi);
        atomicMin(&pp[obase + qi[k]], packed);
    }
}

// ---- fallback (proven R15 LDS kernel) for small workspace ----
#define LOADF8(J) do {                                                        \
    f0 = sv4[8*(J)+0]; f1 = sv4[8*(J)+1]; f2 = sv4[8*(J)+2];                  \
    f3 = sv4[8*(J)+3]; f4 = sv4[8*(J)+4]; f5 = sv4[8*(J)+5];                  \
    f6 = sv4[8*(J)+6]; f7 = sv4[8*(J)+7];                                     \
} while (0)

__global__ __launch_bounds__(256, 4) void chamfer_main_lds(
    const float* __restrict__ xyz1, const float* __restrict__ xyz2,
    unsigned long long* __restrict__ pp,
    int N, int M, int B, int S, int C)
{
    const int dir = blockIdx.z;
    const float* q = dir ? xyz2 : xyz1;
    const float* r = dir ? xyz1 : xyz2;
    const int Nq = dir ? M : N;
    const int Nr = dir ? N : M;
    const int b     = blockIdx.y / S;
    const int split = blockIdx.y % S;
    const int base  = split * C;

    extern __shared__ float s[];
    float4* sv4 = (float4*)s;
    {
        const float* g3 = r + ((size_t)b * Nr + base) * 3;
        for (int t = threadIdx.x; t < C; t += BLK) {
            float gx = g3[3 * t + 0], gy = g3[3 * t + 1], gz = g3[3 * t + 2];
            float rr = fmaf(gz, gz, fmaf(gy, gy, gx * gx));
            float4 f; f.x = gx; f.y = gy; f.z = gz; f.w = rr;
            sv4[t] = f;
        }
    }
    __syncthreads();

    float ax[QPT], ay[QPT], az[QPT];
    int qi[QPT];
    bool qvv[QPT];
#pragma unroll
    for (int k = 0; k < QPT; ++k) {
        qi[k] = blockIdx.x * QPB + k * BLK + threadIdx.x;
        qvv[k] = qi[k] < Nq;
        const float* qp = q + ((size_t)b * Nq + (qvv[k] ? qi[k] : 0)) * 3;
        ax[k] = -2.0f * qp[0]; ay[k] = -2.0f * qp[1]; az[k] = -2.0f * qp[2];
    }
    float e1[QPT], e2[QPT];
    int   g1[QPT];
#pragma unroll
    for (int k = 0; k < QPT; ++k) { e1[k] = INFINITY; e2[k] = INFINITY; g1[k] = 0; }

    const int iters = C / 8;
    for (int j8 = 0; j8 < iters; ++j8) {
        float4 f0, f1, f2, f3, f4, f5, f6, f7;
        LOADF8(j8);
#pragma unroll
        for (int k = 0; k < QPT; ++k) {
            float m;
            EMIN8(ax[k], ay[k], az[k], m);
            float h = fmaxf(e1[k], m);
            e2[k] = fminf(e2[k], h);
            if (m < e1[k]) g1[k] = j8;
            e1[k] = fminf(e1[k], m);
        }
    }

    const size_t obase = (size_t)(dir * B + b) * Nq;
    const int gbase = split * (C / 8);
#pragma unroll
    for (int k = 0; k < QPT; ++k) {
        if (!qvv[k]) continue;
        const float qx = -0.5f * ax[k], qy = -0.5f * ay[k], qz = -0.5f * az[k];
        int gi = g1[k];
        float dwin;
        bool resolved = false;
        {
            float qq  = fmaf(qx, qx, fmaf(qy, qy, qz * qz));
            float d1e = qq + e1[k];
            float rt  = sqrtf(qq) + sqrtf(fmaxf(d1e, 0.0f) + 0.01f);
            float eps = 4e-6f * fmaf(2.0f, rt * rt, qq);
            if (e2[k] - e1[k] <= eps) {
                const float lim = e1[k] + eps;
                unsigned long long mask = 0ull;
                for (int j8 = 0; j8 < iters; ++j8) {
                    float4 f0, f1, f2, f3, f4, f5, f6, f7;
                    LOADF8(j8);
                    float m;
                    EMIN8(ax[k], ay[k], az[k], m);
                    if (m <= lim) mask |= 1ull << j8;
                }
                float bdx = INFINITY; int gs = 0;
                for (int j8 = 0; j8 < iters; ++j8) {
                    if (!((mask >> j8) & 1)) continue;
                    float4 f0, f1, f2, f3, f4, f5, f6, f7;
                    LOADF8(j8);
                    float md;
                    DMIN8(qx, qy, qz, md);
                    if (md < bdx) { bdx = md; gs = j8; }
                }
                gi = gs; dwin = bdx; resolved = true;
            }
        }
        if (!resolved) {
            const float4* rv =
                (const float4*)(r + ((size_t)b * Nr + base + (size_t)gi * 8) * 3);
            float4 h0 = rv[0], h1 = rv[1], h2 = rv[2],
                   h3 = rv[3], h4 = rv[4], h5 = rv[5];
            float px[8] = { h0.x, h0.w, h1.z, h2.y, h3.x, h3.w, h4.z, h5.y };
            float py[8] = { h0.y, h1.x, h1.w, h2.z, h3.y, h4.x, h4.w, h5.z };
            float pz[8] = { h0.z, h1.y, h2.x, h2.w, h3.z, h4.y, h5.x, h5.w };
            float d[8];
#pragma unroll
            for (int p = 0; p < 8; ++p) {
                float dx = qx - px[p];
                float dy = qy - py[p];
                float dz = qz - pz[p];
                d[p] = fmaf(dx, dx, fmaf(dy, dy, dz * dz));
            }
            float t0 = fminf(fminf(d[0], d[1]), d[2]);
            float t1 = fminf(fminf(d[3], d[4]), d[5]);
            float t2 = fminf(fminf(d[6], d[7]), t0);
            dwin = fminf(t1, t2);
        }
        unsigned long long packed =
            ((unsigned long long)__float_as_uint(dwin) << 32)
            | (unsigned)(gbase + gi);
        atomicMin(&pp[obase + qi[k]], packed);
    }
}

__global__ __launch_bounds__(256) void chamfer_final(
    const float* __restrict__ xyz1, const float* __restrict__ xyz2,
    const unsigned long long* __restrict__ pp,
    float* __restrict__ out, int N, int M, int B)
{
    const int gid = blockIdx.x * blockDim.x + threadIdx.x;
    const int perDir0 = B * N;
    int dir, rem;
    if (gid < perDir0) { dir = 0; rem = gid; }
    else if (gid < perDir0 + B * M) { dir = 1; rem = gid - perDir0; }
    else return;
    const int Nq = dir ? M : N;
    const int Nr = dir ? N : M;
    const float* q = dir ? xyz2 : xyz1;
    const float* r = dir ? xyz1 : xyz2;

    unsigned long long v = pp[(size_t)(dir * B) * Nq + rem];
    const unsigned bits = (unsigned)(v >> 32);
    const int grp = (int)(v & 0xffffffffu);

    const int b  = rem / Nq;
    const int qi = rem - b * Nq;
    const float* qp = q + ((size_t)b * Nq + qi) * 3;
    const float qx = qp[0], qy = qp[1], qz = qp[2];

    const float4* rv = (const float4*)(r + ((size_t)b * Nr + (size_t)grp * 8) * 3);
    float4 f0 = rv[0], f1 = rv[1], f2 = rv[2], f3 = rv[3], f4 = rv[4], f5 = rv[5];
    float px[8] = { f0.x, f0.w, f1.z, f2.y, f3.x, f3.w, f4.z, f5.y };
    float py[8] = { f0.y, f1.x, f1.w, f2.z, f3.y, f4.x, f4.w, f5.z };
    float pz[8] = { f0.z, f1.y, f2.x, f2.w, f3.z, f4.y, f5.x, f5.w };
    int best = 0;
#pragma unroll
    for (int p = 7; p >= 0; --p) {       // descending: ends at SMALLEST match
        float dx = qx - px[p];
        float dy = qy - py[p];
        float dz = qz - pz[p];
        float d = fmaf(dx, dx, fmaf(dy, dy, dz * dz));
        if (__float_as_uint(d) == bits) best = p;
    }
    const int idx = grp * 8 + best;

    float* dist_out = out + (dir ? (size_t)B * N : 0);
    float* idx_out  = out + (size_t)B * N + (size_t)B * M + (dir ? (size_t)B * N : 0);
    dist_out[rem] = __uint_as_float(bits);
    idx_out[rem]  = (float)idx;
}

extern "C" void kernel_launch(void* const* d_in, const int* in_sizes, int n_in,
                              void* d_out, int out_size, void* d_ws, size_t ws_size,
                              hipStream_t stream) {
    const float* xyz1 = (const float*)d_in[0];
    const float* xyz2 = (const float*)d_in[1];
    float* out = (float*)d_out;
    const int B = 4;
    const int N = in_sizes[0] / (B * 3);
    const int M = in_sizes[1] / (B * 3);
    const int NQ = (N > M ? N : M);
    const int NR = (N > M ? N : M);

    int S = 32;
    while (NR % (S * 8)) S >>= 1;  // need C = NR/S divisible by 8
    const int C = NR / S;          // C/8 groups <= 64 (u64 mask)

    unsigned long long* pp = (unsigned long long*)d_ws;  // [2][B][NQ]
    const int nslots = 2 * B * NQ;
    const size_t ppBytes  = (size_t)nslots * 8;
    const size_t augElems = (size_t)B * N + (size_t)B * M;
    const size_t needed   = ppBytes + augElems * sizeof(float4);

    hipMemsetAsync(pp, 0xFF, ppBytes, stream);

    dim3 grid((NQ + QPB - 1) / QPB, B * S, 2);
    if (ws_size >= needed) {
        float4* aug = (float4*)((char*)d_ws + ppBytes);
        chamfer_prep<<<dim3((augElems + 255) / 256, 1, 1), dim3(256, 1, 1), 0,
                       stream>>>(xyz1, xyz2, aug, B * N, (int)augElems);
        chamfer_main_aug<<<grid, dim3(BLK, 1, 1), 0, stream>>>(
            xyz1, xyz2, aug, pp, N, M, B, S, C);
    } else {
        size_t lds = (size_t)C * 4 * sizeof(float);
        chamfer_main_lds<<<grid, dim3(BLK, 1, 1), lds, stream>>>(
            xyz1, xyz2, pp, N, M, B, S, C);
    }

    chamfer_final<<<dim3((nslots + 255) / 256, 1, 1), dim3(256, 1, 1), 0, stream>>>(
        xyz1, xyz2, pp, out, N, M, B);
}

// Round 8
// 120.466 us; speedup vs baseline: 1.1398x; 1.1398x over previous
//
#include <hip/hip_runtime.h>
#include <math.h>

// Chamfer distance, B=4, N=M=8192, fp32.
// Output layout (flat float32): dist1[B*N], dist2[B*M], idx1[B*N] (as float),
// idx2[B*M] (as float).
//
// R17: R15 kernel (e-form + guard, LDS staging — proven absmax 0, conflicts
// 0) with QPT 4 -> 8. R16 falsified "move tile reads to global" (86us; VMEM
// latency + 3x FETCH). The surviving model: R15 = ~41us DS-pipe (32 waves/CU
// x 256 broadcast ds_read_b128 x ~12cy) + ~28us VALU, nearly additive. The
// DS term is pure redundancy - every wave re-reads the same 4KB tile. QPT=8
// halves the wave count (each wave serves 8 queries/lane), halving aggregate
// DS time; aggregate VALU is unchanged. Predicted main ~52-60us.
// ~100 VGPR expected (fits launch_bounds(256,4) cap of 128, no spill).
//
// Guard (unchanged): e = fma(ax,rx,fma(ay,ry,fma(az,rz,rr))), a=-2q exact,
// rr=|r|^2 staged in LDS float4.w. If top-2 group-min e-gap <=
// eps=4e-6*(qq+2Rb) (2x margin over the ~1.9e-6*(qq+2Rb) bound,
// Rb=(|q|+sqrt(d1+.01))^2), replay the e-pass (same input bits -> bitwise
// same) to build a contender bitmask, then resolve exactly with R12's d-form
// ascending strict-< scan. Unflagged winner group provably == R12's; its
// exact d comes from a divergent global gather (L1/L2-resident, raw xyz,
// same bits as LDS copy). Same (d_bits<<32|global_group) atomicMin;
// chamfer_final unchanged -> outputs bitwise identical to R12/R15.
//
// Tie semantics: equal d bits -> atomicMin picks smallest global group;
// chamfer_final's descending scan ends at smallest matching p == np.argmin
// first-occurrence.
//
// R13 lesson: named float4s + constant-index (unrolled) scalars only.

#define QPT 8         // queries per thread  (R17: was 4)
#define BLK 256       // threads per block
#define QPB (QPT*BLK) // queries per block = 2048

// load 8 ref float4s (one group) from LDS into named registers
#define LOADF8(J) do {                                                        \
    f0 = sv4[8*(J)+0]; f1 = sv4[8*(J)+1]; f2 = sv4[8*(J)+2];                  \
    f3 = sv4[8*(J)+3]; f4 = sv4[8*(J)+4]; f5 = sv4[8*(J)+5];                  \
    f6 = sv4[8*(J)+6]; f7 = sv4[8*(J)+7];                                     \
} while (0)

// e-form group min over named float4s f0..f7
#define EMIN8(AX, AY, AZ, MOUT) do {                                          \
    float d0 = fmaf(AX, f0.x, fmaf(AY, f0.y, fmaf(AZ, f0.z, f0.w)));          \
    float d1 = fmaf(AX, f1.x, fmaf(AY, f1.y, fmaf(AZ, f1.z, f1.w)));          \
    float d2 = fmaf(AX, f2.x, fmaf(AY, f2.y, fmaf(AZ, f2.z, f2.w)));          \
    float d3 = fmaf(AX, f3.x, fmaf(AY, f3.y, fmaf(AZ, f3.z, f3.w)));          \
    float d4 = fmaf(AX, f4.x, fmaf(AY, f4.y, fmaf(AZ, f4.z, f4.w)));          \
    float d5 = fmaf(AX, f5.x, fmaf(AY, f5.y, fmaf(AZ, f5.z, f5.w)));          \
    float d6 = fmaf(AX, f6.x, fmaf(AY, f6.y, fmaf(AZ, f6.z, f6.w)));          \
    float d7 = fmaf(AX, f7.x, fmaf(AY, f7.y, fmaf(AZ, f7.z, f7.w)));          \
    float t0 = fminf(fminf(d0, d1), d2);                                      \
    float t1 = fminf(fminf(d3, d4), d5);                                      \
    float t2 = fminf(fminf(d6, d7), t0);                                      \
    MOUT = fminf(t1, t2);                                                     \
} while (0)

// exact d-form group min over named float4s f0..f7 (R12 expression; min is
// exact and tree-shape independent -> bitwise-compatible with chamfer_final)
#define DMIN8(QX, QY, QZ, MOUT) do {                                          \
    float dx, dy, dz;                                                         \
    dx = QX - f0.x; dy = QY - f0.y; dz = QZ - f0.z;                           \
    float d0 = fmaf(dx, dx, fmaf(dy, dy, dz * dz));                           \
    dx = QX - f1.x; dy = QY - f1.y; dz = QZ - f1.z;                           \
    float d1 = fmaf(dx, dx, fmaf(dy, dy, dz * dz));                           \
    dx = QX - f2.x; dy = QY - f2.y; dz = QZ - f2.z;                           \
    float d2 = fmaf(dx, dx, fmaf(dy, dy, dz * dz));                           \
    dx = QX - f3.x; dy = QY - f3.y; dz = QZ - f3.z;                           \
    float d3 = fmaf(dx, dx, fmaf(dy, dy, dz * dz));                           \
    dx = QX - f4.x; dy = QY - f4.y; dz = QZ - f4.z;                           \
    float d4 = fmaf(dx, dx, fmaf(dy, dy, dz * dz));                           \
    dx = QX - f5.x; dy = QY - f5.y; dz = QZ - f5.z;                           \
    float d5 = fmaf(dx, dx, fmaf(dy, dy, dz * dz));                           \
    dx = QX - f6.x; dy = QY - f6.y; dz = QZ - f6.z;                           \
    float d6 = fmaf(dx, dx, fmaf(dy, dy, dz * dz));                           \
    dx = QX - f7.x; dy = QY - f7.y; dz = QZ - f7.z;                           \
    float d7 = fmaf(dx, dx, fmaf(dy, dy, dz * dz));                           \
    float t0 = fminf(fminf(d0, d1), d2);                                      \
    float t1 = fminf(fminf(d3, d4), d5);                                      \
    float t2 = fminf(fminf(d6, d7), t0);                                      \
    MOUT = fminf(t1, t2);                                                     \
} while (0)

__global__ __launch_bounds__(256, 4) void chamfer_main(
    const float* __restrict__ xyz1, const float* __restrict__ xyz2,
    unsigned long long* __restrict__ pp,
    int N, int M, int B, int S, int C)
{
    const int dir = blockIdx.z;          // 0: xyz1->xyz2, 1: xyz2->xyz1
    const float* q = dir ? xyz2 : xyz1;  // query cloud
    const float* r = dir ? xyz1 : xyz2;  // reference cloud
    const int Nq = dir ? M : N;
    const int Nr = dir ? N : M;
    const int b     = blockIdx.y / S;
    const int split = blockIdx.y % S;
    const int base  = split * C;         // this block's ref-index range

    extern __shared__ float s[];         // C float4s: (x,y,z,rr)
    float4* sv4 = (float4*)s;

    // stage tile: repack packed-xyz -> float4(x,y,z,rr). rr deterministic
    // per point; only feeds e-comparisons (never output values).
    {
        const float* g3 = r + ((size_t)b * Nr + base) * 3;
        for (int t = threadIdx.x; t < C; t += BLK) {
            float gx = g3[3 * t + 0], gy = g3[3 * t + 1], gz = g3[3 * t + 2];
            float rr = fmaf(gz, gz, fmaf(gy, gy, gx * gx));
            float4 f; f.x = gx; f.y = gy; f.z = gz; f.w = rr;
            sv4[t] = f;
        }
    }
    __syncthreads();

    // load QPT query points; keep a = -2*q (exact; q recoverable as -0.5*a)
    float ax[QPT], ay[QPT], az[QPT];
    bool qvv[QPT];
#pragma unroll
    for (int k = 0; k < QPT; ++k) {
        const int qidx = blockIdx.x * QPB + k * BLK + threadIdx.x;
        qvv[k] = qidx < Nq;
        const float* qp = q + ((size_t)b * Nq + (qvv[k] ? qidx : 0)) * 3;
        ax[k] = -2.0f * qp[0]; ay[k] = -2.0f * qp[1]; az[k] = -2.0f * qp[2];
    }

    // per-query: top-2 group-min e values + winning group id
    float e1[QPT], e2[QPT];
    int   g1[QPT];
#pragma unroll
    for (int k = 0; k < QPT; ++k) { e1[k] = INFINITY; e2[k] = INFINITY; g1[k] = 0; }

    const int iters = C / 8;             // <= 64 (mask is u64)
    for (int j8 = 0; j8 < iters; ++j8) {
        float4 f0, f1, f2, f3, f4, f5, f6, f7;
        LOADF8(j8);                      // all lanes same addr -> LDS broadcast
#pragma unroll
        for (int k = 0; k < QPT; ++k) {
            float m;
            EMIN8(ax[k], ay[k], az[k], m);
            float h = fmaxf(e1[k], m);
            e2[k] = fminf(e2[k], h);     // runner-up group-min
            if (m < e1[k]) g1[k] = j8;   // strict <: earliest group on e-ties
            e1[k] = fminf(e1[k], m);
        }
    }

    const size_t obase = (size_t)(dir * B + b) * Nq;
    const int gbase = split * (C / 8);   // global group base for this block
#pragma unroll
    for (int k = 0; k < QPT; ++k) {
        if (!qvv[k]) continue;
        const int qidx = blockIdx.x * QPB + k * BLK + threadIdx.x;
        // exact query coords (bitwise original: a = -2q exact, -0.5*a = q)
        const float qx = -0.5f * ax[k], qy = -0.5f * ay[k], qz = -0.5f * az[k];
        int gi = g1[k];
        float dwin;
        bool resolved = false;
        {
            // eps: contenders have rr <= Rb=(|q|+sqrt(d1e+0.01))^2; e-chain
            // error < ~1.9e-6*(qq+2Rb); use 4e-6 (2x margin).
            float qq  = fmaf(qx, qx, fmaf(qy, qy, qz * qz));
            float d1e = qq + e1[k];
            float rt  = sqrtf(qq) + sqrtf(fmaxf(d1e, 0.0f) + 0.01f);
            float eps = 4e-6f * fmaf(2.0f, rt * rt, qq);
            if (e2[k] - e1[k] <= eps) {
                // replay e-pass (same inputs -> bitwise same) -> contender mask
                const float lim = e1[k] + eps;
                unsigned long long mask = 0ull;
                for (int j8 = 0; j8 < iters; ++j8) {
                    float4 f0, f1, f2, f3, f4, f5, f6, f7;
                    LOADF8(j8);          // uniform addr -> broadcast
                    float m;
                    EMIN8(ax[k], ay[k], az[k], m);
                    if (m <= lim) mask |= 1ull << j8;
                }
                // exact resolve with R12's d-form + semantics (earliest group)
                float bdx = INFINITY; int gs = 0;
                for (int j8 = 0; j8 < iters; ++j8) {
                    if (!((mask >> j8) & 1)) continue;
                    float4 f0, f1, f2, f3, f4, f5, f6, f7;
                    LOADF8(j8);          // uniform addr -> broadcast
                    float md;
                    DMIN8(qx, qy, qz, md);
                    if (md < bdx) { bdx = md; gs = j8; }
                }
                gi = gs; dwin = bdx; resolved = true;
            }
        }
        if (!resolved) {
            // exact d-form min of winner group via divergent GLOBAL gather
            // (L1/L2-resident raw xyz; same bits -> identical d bits; no LDS
            // bank conflicts - R14 lesson).
            const float4* rv =
                (const float4*)(r + ((size_t)b * Nr + base + (size_t)gi * 8) * 3);
            float4 h0 = rv[0], h1 = rv[1], h2 = rv[2],
                   h3 = rv[3], h4 = rv[4], h5 = rv[5];
            float px[8] = { h0.x, h0.w, h1.z, h2.y, h3.x, h3.w, h4.z, h5.y };
            float py[8] = { h0.y, h1.x, h1.w, h2.z, h3.y, h4.x, h4.w, h5.z };
            float pz[8] = { h0.z, h1.y, h2.x, h2.w, h3.z, h4.y, h5.x, h5.w };
            float d[8];
#pragma unroll
            for (int p = 0; p < 8; ++p) {
                float dx = qx - px[p];
                float dy = qy - py[p];
                float dz = qz - pz[p];
                d[p] = fmaf(dx, dx, fmaf(dy, dy, dz * dz));
            }
            float t0 = fminf(fminf(d[0], d[1]), d[2]);
            float t1 = fminf(fminf(d[3], d[4]), d[5]);
            float t2 = fminf(fminf(d[6], d[7]), t0);
            dwin = fminf(t1, t2);
        }
        unsigned long long packed =
            ((unsigned long long)__float_as_uint(dwin) << 32)
            | (unsigned)(gbase + gi);
        atomicMin(&pp[obase + qidx], packed);
    }
}

__global__ __launch_bounds__(256) void chamfer_final(
    const float* __restrict__ xyz1, const float* __restrict__ xyz2,
    const unsigned long long* __restrict__ pp,
    float* __restrict__ out, int N, int M, int B)
{
    const int gid = blockIdx.x * blockDim.x + threadIdx.x;
    const int perDir0 = B * N;
    int dir, rem;
    if (gid < perDir0) { dir = 0; rem = gid; }
    else if (gid < perDir0 + B * M) { dir = 1; rem = gid - perDir0; }
    else return;
    const int Nq = dir ? M : N;
    const int Nr = dir ? N : M;
    const float* q = dir ? xyz2 : xyz1;
    const float* r = dir ? xyz1 : xyz2;

    // pp is [2][B][Nq] flat; rem = b*Nq + i
    unsigned long long v = pp[(size_t)(dir * B) * Nq + rem];
    const unsigned bits = (unsigned)(v >> 32);
    const int grp = (int)(v & 0xffffffffu);

    const int b  = rem / Nq;
    const int qi = rem - b * Nq;
    const float* qp = q + ((size_t)b * Nq + qi) * 3;
    const float qx = qp[0], qy = qp[1], qz = qp[2];

    // gather the winning 8-point group from global (L2-resident), recompute
    // with the SAME fmaf expression on the SAME input bits -> bitwise match.
    const float4* rv = (const float4*)(r + ((size_t)b * Nr + (size_t)grp * 8) * 3);
    float4 f0 = rv[0], f1 = rv[1], f2 = rv[2], f3 = rv[3], f4 = rv[4], f5 = rv[5];
    float px[8] = { f0.x, f0.w, f1.z, f2.y, f3.x, f3.w, f4.z, f5.y };
    float py[8] = { f0.y, f1.x, f1.w, f2.z, f3.y, f4.x, f4.w, f5.z };
    float pz[8] = { f0.z, f1.y, f2.x, f2.w, f3.z, f4.y, f5.x, f5.w };
    int best = 0;
#pragma unroll
    for (int p = 7; p >= 0; --p) {       // descending: ends at SMALLEST match
        float dx = qx - px[p];
        float dy = qy - py[p];
        float dz = qz - pz[p];
        float d = fmaf(dx, dx, fmaf(dy, dy, dz * dz));
        if (__float_as_uint(d) == bits) best = p;  // match guaranteed (same bits)
    }
    const int idx = grp * 8 + best;

    float* dist_out = out + (dir ? (size_t)B * N : 0);
    float* idx_out  = out + (size_t)B * N + (size_t)B * M + (dir ? (size_t)B * N : 0);
    dist_out[rem] = __uint_as_float(bits);
    idx_out[rem]  = (float)idx;
}

extern "C" void kernel_launch(void* const* d_in, const int* in_sizes, int n_in,
                              void* d_out, int out_size, void* d_ws, size_t ws_size,
                              hipStream_t stream) {
    const float* xyz1 = (const float*)d_in[0];
    const float* xyz2 = (const float*)d_in[1];
    float* out = (float*)d_out;
    const int B = 4;
    const int N = in_sizes[0] / (B * 3);
    const int M = in_sizes[1] / (B * 3);
    const int NQ = (N > M ? N : M);
    const int NR = (N > M ? N : M);

    int S = 32;
    while (NR % (S * 8)) S >>= 1;  // need C = NR/S divisible by 8
    const int C = NR / S;          // C/8 groups <= 64 (u64 mask)

    unsigned long long* pp = (unsigned long long*)d_ws;  // [2][B][NQ] packed slots
    const int nslots = 2 * B * NQ;

    // init pp to ~0ULL via byte-pattern memset (0xFF) — graph-capturable
    // memset node, replaces the init kernel (one fewer dispatch + gap).
    hipMemsetAsync(pp, 0xFF, (size_t)nslots * 8, stream);

    dim3 grid((NQ + QPB - 1) / QPB, B * S, 2);
    size_t lds = (size_t)C * 4 * sizeof(float);   // float4 per ref point
    chamfer_main<<<grid, dim3(BLK, 1, 1), lds, stream>>>(
        xyz1, xyz2, pp, N, M, B, S, C);

    chamfer_final<<<dim3((nslots + 255) / 256, 1, 1), dim3(256, 1, 1), 0, stream>>>(
        xyz1, xyz2, pp, out, N, M, B);
}